// Round 11
// baseline (196.209 us; speedup 1.0000x reference)
//
#include <hip/hip_runtime.h>
#include <hip/hip_bf16.h>
#include <float.h>
#include <math.h>

#define RGB_H 288
#define RGB_W 256
#define NCH 10
#define NCH_PAD 12
#define HM_N 2
#define HM_S 640
#define MAX_DET_K 15
#define IPT 4                 // points per thread in paint (VGPR ~100, good occupancy)
#define PBLK (256 * IPT)      // 1024 points per block

// native vector types (HIP float4 is a struct; nontemporal builtins need these)
typedef float f4 __attribute__((ext_vector_type(4)));
typedef float f2 __attribute__((ext_vector_type(2)));

// peak tiles
#define TW 64
#define TH 16
#define SW (TW + 6)   // 70
#define SP 72         // padded LDS row stride
#define SH (TH + 6)   // 22
#define NTILE_X (HM_S / TW)              // 10
#define NTILE_Y (HM_S / TH)              // 40
#define TILES_PER_MAP (NTILE_X * NTILE_Y) // 400
#define S1N (TILES_PER_MAP * MAX_DET_K)   // 6000 entries per map
#define RPT 24                            // merge: register entries per thread

#define TP_TOTAL (3 * RGB_H * RGB_W)
#define TP_BLOCKS ((TP_TOTAL + 255) / 256)        // 864
#define PEAK_BLOCKS (TILES_PER_MAP * HM_N)        // 800

// ---------------- ws layout ----------------
#define WS_S1SCORE  0
#define WS_S1IDX    (WS_S1SCORE + HM_N * S1N * 4)
#define WS_DONE     (WS_S1IDX + HM_N * S1N * 4)
#define WS_PSEMS    ((WS_DONE + 16 + 63) & ~63)
#define PSEMS_BYTES ((size_t)TP_TOTAL * NCH_PAD * 4)

// ---------------------------------------------------------------------------
// K1: sems transpose [cam][c][v][u] -> psems [cam][v][u][c pad12]
//     + zero the per-map done counters (ws is re-poisoned before every call).
// ---------------------------------------------------------------------------
__global__ __launch_bounds__(256) void prep_kernel(
    const float* __restrict__ sems,
    float* __restrict__ ps,
    int* __restrict__ done,
    int use_ps)
{
    if (blockIdx.x == 0 && threadIdx.x < HM_N) done[threadIdx.x] = 0;
    if (!use_ps) return;
    const int t = blockIdx.x * 256 + threadIdx.x;
    if (t >= TP_TOTAL) return;
    const int u = t & (RGB_W - 1);
    const int v = (t >> 8) % RGB_H;
    const int cam = t / (RGB_H * RGB_W);
    float vals[NCH_PAD];
#pragma unroll
    for (int c = 0; c < NCH; ++c)
        vals[c] = sems[(((long long)cam * NCH + c) * RGB_H + v) * RGB_W + u];
    vals[10] = 0.0f; vals[11] = 0.0f;
    f4* dst = (f4*)(ps + (size_t)t * NCH_PAD);
    dst[0] = (f4){vals[0], vals[1], vals[2],  vals[3]};
    dst[1] = (f4){vals[4], vals[5], vals[6],  vals[7]};
    dst[2] = (f4){vals[8], vals[9], vals[10], vals[11]};
}

// ---------------------------------------------------------------------------
// K2: fused  [peaks blocks 0..799 (last tile per map also merges) | paint]
// Peaks no longer gate paint (they run concurrently); merge runs in the
// last-finishing tile-block of its map via device-scope atomicAdd +
// __threadfence (no spin-wait -> no dispatch-order assumption, G16-safe).
// Paint projection arithmetic identical to R1 — do not touch rounding.
// ---------------------------------------------------------------------------
__global__ __launch_bounds__(256) void main_kernel(
    const float* __restrict__ lidar,
    const float* __restrict__ sems,
    const float* __restrict__ psems,
    int use_ps,
    const float* __restrict__ Km,
    const float* __restrict__ L2W,
    const float* __restrict__ W2C,
    const float* __restrict__ hm,
    float* __restrict__ out,
    int N,
    float* s1score,
    int* s1idx,
    int* done,
    float* __restrict__ out_scores,
    float* __restrict__ out_locs)
{
    const int tid = threadIdx.x;

    if (blockIdx.x < PEAK_BLOCKS) {
        // ==== peaks: separable 7x7 SAME max-pool peak detect + tile top-15
        __shared__ float sA[SH * SP];
        __shared__ float hx[SH * TW];
        __shared__ float lsc[TW * TH];
        __shared__ int   lix[TW * TH];
        __shared__ int   lcnt;
        __shared__ int   do_merge;

        const int bid = blockIdx.x;
        const int m  = bid / TILES_PER_MAP;
        const int tt = bid % TILES_PER_MAP;
        const int gx0 = (tt % NTILE_X) * TW;
        const int gy0 = (tt / NTILE_X) * TH;
        const int tx = tid & 63;
        const int ty = tid >> 6;     // 0..3
        const float* h = hm + (long long)m * HM_S * HM_S;

        if (tid == 0) lcnt = 0;
        __syncthreads();

        for (int yy = ty; yy < SH; yy += 4) {
            const int gv = gy0 + yy - 3;
            const bool vok = (gv >= 0) & (gv < HM_S);
            for (int xx = tx; xx < SW; xx += 64) {
                const int gu = gx0 + xx - 3;
                float val = -INFINITY;
                if (vok & (gu >= 0) & (gu < HM_S)) val = h[gv * HM_S + gu];
                sA[yy * SP + xx] = val;
            }
        }
        __syncthreads();

        for (int yy = ty; yy < SH; yy += 4) {
            const float* r = sA + yy * SP + tx;
            float mx = r[0];
#pragma unroll
            for (int k = 1; k < 7; ++k) mx = fmaxf(mx, r[k]);
            hx[yy * TW + tx] = mx;
        }
        __syncthreads();

        for (int ry = ty; ry < TH; ry += 4) {
            const float val = sA[(ry + 3) * SP + tx + 3];
            float mx = hx[ry * TW + tx];
#pragma unroll
            for (int k = 1; k < 7; ++k) mx = fmaxf(mx, hx[(ry + k) * TW + tx]);
            if (!(mx > val)) {
                int pos = atomicAdd(&lcnt, 1);   // LDS atomic
                lsc[pos] = val;
                lix[pos] = (gy0 + ry) * HM_S + (gx0 + tx);
            }
        }
        __syncthreads();

        // wave 0: 15 x argmax over the (avg ~20) local candidates
        if (tid < 64) {
            const int n = lcnt;
            const int slot0 = (m * TILES_PER_MAP + tt) * MAX_DET_K;
            for (int t = 0; t < MAX_DET_K; ++t) {
                float bs = -INFINITY; int bi = 0x7fffffff; int bp = -1;
                for (int j = tid; j < n; j += 64) {
                    const float s = lsc[j]; const int id = lix[j];
                    if (s > bs || (s == bs && id < bi)) { bs = s; bi = id; bp = j; }
                }
#pragma unroll
                for (int off = 32; off > 0; off >>= 1) {
                    const float os = __shfl_down(bs, off);
                    const int   oi = __shfl_down(bi, off);
                    const int   op = __shfl_down(bp, off);
                    if (os > bs || (os == bs && oi < bi)) { bs = os; bi = oi; bp = op; }
                }
                bs = __shfl(bs, 0); bi = __shfl(bi, 0); bp = __shfl(bp, 0);
                if (tid == 0) {
                    s1score[slot0 + t] = bs;
                    s1idx[slot0 + t]   = bi;
                    if (bp >= 0) lsc[bp] = -INFINITY;
                }
            }
        }
        __syncthreads();

        // ==== release + count; last tile of this map merges
        if (tid == 0) {
            __threadfence();                       // publish s1 writes device-wide
            const int d = atomicAdd(&done[m], 1);  // device-scope
            do_merge = (d == TILES_PER_MAP - 1);
        }
        __syncthreads();
        if (!do_merge) return;
        __threadfence();                           // acquire: see all tiles' s1

        // ==== merge: top-15 of 6000 entries, 24 register entries/thread
        {
            const int lane = tid & 63;
            const int wv = tid >> 6;   // 0..3
            float es[RPT]; int ei[RPT];
#pragma unroll
            for (int e = 0; e < RPT; ++e) {
                const int j = e * 256 + tid;
                if (j < S1N) { es[e] = s1score[m * S1N + j]; ei[e] = s1idx[m * S1N + j]; }
                else         { es[e] = -INFINITY;            ei[e] = 0x7fffffff; }
            }

            __shared__ float bss[4];
            __shared__ int   bis[4];
            __shared__ int   bps[4];
            __shared__ int   fbp;

            for (int t = 0; t < MAX_DET_K; ++t) {
                float bs = -INFINITY; int bi = 0x7fffffff; int bp = -1;
#pragma unroll
                for (int e = 0; e < RPT; ++e) {
                    if (es[e] > bs || (es[e] == bs && ei[e] < bi)) {
                        bs = es[e]; bi = ei[e]; bp = e * 256 + tid;
                    }
                }
#pragma unroll
                for (int off = 32; off > 0; off >>= 1) {
                    const float os = __shfl_down(bs, off);
                    const int   oi = __shfl_down(bi, off);
                    const int   op = __shfl_down(bp, off);
                    if (os > bs || (os == bs && oi < bi)) { bs = os; bi = oi; bp = op; }
                }
                if (lane == 0) { bss[wv] = bs; bis[wv] = bi; bps[wv] = bp; }
                __syncthreads();
                if (tid == 0) {
                    float s = bss[0]; int i0 = bis[0]; int p = bps[0];
#pragma unroll
                    for (int w = 1; w < 4; ++w) {
                        if (bss[w] > s || (bss[w] == s && bis[w] < i0)) {
                            s = bss[w]; i0 = bis[w]; p = bps[w];
                        }
                    }
                    out_scores[m * MAX_DET_K + t] = s;
                    out_locs[m * MAX_DET_K + t]   = (float)i0;
                    fbp = p;
                }
                __syncthreads();
                const int wbp = fbp;
                if (wbp >= 0 && (wbp & 255) == tid) es[wbp >> 8] = -INFINITY;
                __syncthreads();
            }
        }
        return;
    }

    // ==== paint: 4 points/thread, no LDS, 12 gathers in flight
    const long long base = (long long)(blockIdx.x - PEAK_BLOCKS) * PBLK;

    long long gofs[IPT];   // psems pixel offset, -1 invalid, -2 out of range
#pragma unroll
    for (int k = 0; k < IPT; ++k) {
        const long long p = base + k * 256 + tid;
        f4 pt = (f4){0.f, 0.f, 0.f, 0.f};
        if (p < N) pt = __builtin_nontemporal_load(((const f4*)lidar) + p);
        const float x = pt.x, y = pt.y, z = pt.z;

        float w[3];
#pragma unroll
        for (int i = 0; i < 3; ++i) {
            float acc = L2W[4*i+0] * x;
            acc = fmaf(L2W[4*i+1], y, acc);
            acc = fmaf(L2W[4*i+2], z, acc);
            acc = fmaf(L2W[4*i+3], 1.0f, acc);
            w[i] = acc;
        }

        int sel = -1, su = 0, sv = 0;
#pragma unroll
        for (int i = 0; i < 3; ++i) {
            const float* W = W2C + 16 * i;
            float cam[3];
#pragma unroll
            for (int r = 0; r < 3; ++r) {
                float acc = W[4*r+0] * w[0];
                acc = fmaf(W[4*r+1], w[1], acc);
                acc = fmaf(W[4*r+2], w[2], acc);
                acc = fmaf(W[4*r+3], 1.0f, acc);
                cam[r] = acc;
            }
            const float c30 = cam[1], c31 = -cam[2], c32 = cam[0];
            float pr[3];
#pragma unroll
            for (int r = 0; r < 3; ++r) {
                float acc = Km[3*r+0] * c30;
                acc = fmaf(Km[3*r+1], c31, acc);
                acc = fmaf(Km[3*r+2], c32, acc);
                pr[r] = acc;
            }
            const float zz = 1e-5f + pr[2];
            const int u  = __float2int_rz(pr[0] / zz);
            const int v  = __float2int_rz(pr[1] / zz);
            const int zi = __float2int_rz(pr[2]);
            const bool valid = (zi >= 0) & (u >= 0) & (u < RGB_W)
                             & (v >= 0) & (v < RGB_H);
            if (valid) { sel = i; su = u; sv = v; }
        }
        gofs[k] = (sel >= 0)
                ? ((long long)sel * RGB_H + sv) * RGB_W + su
                : -1;
        if (p >= N) gofs[k] = -2;  // fully skip
    }

    f4 ga[IPT], gb[IPT]; f2 gc[IPT];
    if (use_ps) {
#pragma unroll
        for (int k = 0; k < IPT; ++k) {
            ga[k] = (f4){0,0,0,0}; gb[k] = (f4){0,0,0,0}; gc[k] = (f2){0,0};
            if (gofs[k] >= 0) {
                const f4* g = (const f4*)(psems + gofs[k] * NCH_PAD);
                ga[k] = g[0]; gb[k] = g[1];
                const f2* g2 = (const f2*)(g + 2);
                gc[k] = g2[0];
            }
        }
    } else {
#pragma unroll
        for (int k = 0; k < IPT; ++k) {
            ga[k] = (f4){0,0,0,0}; gb[k] = (f4){0,0,0,0}; gc[k] = (f2){0,0};
            if (gofs[k] >= 0) {
                const int sel = (int)(gofs[k] / (RGB_H * RGB_W));
                const int pix = (int)(gofs[k] % (RGB_H * RGB_W));
                const float* s = sems + ((long long)sel * NCH) * RGB_H * RGB_W + pix;
                const long long pl = (long long)RGB_H * RGB_W;
                ga[k] = (f4){s[0], s[pl], s[2*pl], s[3*pl]};
                gb[k] = (f4){s[4*pl], s[5*pl], s[6*pl], s[7*pl]};
                gc[k] = (f2){s[8*pl], s[9*pl]};
            }
        }
    }

#pragma unroll
    for (int k = 0; k < IPT; ++k) {
        const long long p = base + k * 256 + tid;
        if (gofs[k] == -2) continue;
        f2* o = (f2*)(out + p * NCH);   // p*40 bytes — always 8-aligned
        o[0] = (f2){ga[k].x, ga[k].y};
        o[1] = (f2){ga[k].z, ga[k].w};
        o[2] = (f2){gb[k].x, gb[k].y};
        o[3] = (f2){gb[k].z, gb[k].w};
        o[4] = gc[k];
    }
}

extern "C" void kernel_launch(void* const* d_in, const int* in_sizes, int n_in,
                              void* d_out, int out_size, void* d_ws, size_t ws_size,
                              hipStream_t stream)
{
    const float* lidar = (const float*)d_in[0];
    const float* sems  = (const float*)d_in[1];
    const float* hm    = (const float*)d_in[2];
    const float* Km    = (const float*)d_in[3];
    const float* L2W   = (const float*)d_in[4];
    const float* W2C   = (const float*)d_in[5];
    float* out = (float*)d_out;
    const int N = in_sizes[0] / 4;

    char* ws = (char*)d_ws;
    float* s1score = (float*)(ws + WS_S1SCORE);
    int*   s1idx   = (int*)(ws + WS_S1IDX);
    int*   done    = (int*)(ws + WS_DONE);
    float* psems   = (float*)(ws + WS_PSEMS);
    const int use_ps = (ws_size >= (size_t)WS_PSEMS + PSEMS_BYTES) ? 1 : 0;

    // K1: transpose + zero done counters
    prep_kernel<<<TP_BLOCKS, 256, 0, stream>>>(sems, psems, done, use_ps);

    // K2: peaks (0..799, last tile merges) + paint (rest)
    float* out_scores = out + (long long)N * NCH;
    float* out_locs   = out_scores + HM_N * MAX_DET_K;
    const int paint_blocks = (int)((N + PBLK - 1) / PBLK);
    main_kernel<<<PEAK_BLOCKS + paint_blocks, 256, 0, stream>>>(
        lidar, sems, psems, use_ps, Km, L2W, W2C, hm, out, N,
        s1score, s1idx, done, out_scores, out_locs);
}

// Round 12
// 155.977 us; speedup vs baseline: 1.2579x; 1.2579x over previous
//
#include <hip/hip_runtime.h>
#include <hip/hip_bf16.h>
#include <float.h>
#include <math.h>

#define RGB_H 288
#define RGB_W 256
#define NCH 10
#define NCH_PAD 12
#define HM_N 2
#define HM_S 640
#define MAX_DET_K 15
#define IPT 4                 // points per thread in paint (VGPR ~100, 4+ waves/SIMD)
#define PBLK (256 * IPT)      // 1024 points per block

// native vector types (HIP float4 is a struct; nontemporal builtins need these)
typedef float f4 __attribute__((ext_vector_type(4)));
typedef float f2 __attribute__((ext_vector_type(2)));

// peak tiles
#define TW 64
#define TH 16
#define SW (TW + 6)   // 70
#define SP 72         // padded LDS row stride
#define SH (TH + 6)   // 22
#define NTILE_X (HM_S / TW)              // 10
#define NTILE_Y (HM_S / TH)              // 40
#define TILES_PER_MAP (NTILE_X * NTILE_Y) // 400
#define S1N (TILES_PER_MAP * MAX_DET_K)   // 6000 entries per map
#define RPT 24                            // merge: register entries per thread

#define TP_TOTAL (3 * RGB_H * RGB_W)
#define TP_BLOCKS ((TP_TOTAL + 255) / 256)        // 864
#define PEAK_BLOCKS (TILES_PER_MAP * HM_N)        // 800

// ---------------- ws layout ----------------
#define WS_S1SCORE  0
#define WS_S1IDX    (WS_S1SCORE + HM_N * S1N * 4)
#define WS_PSEMS    ((WS_S1IDX + HM_N * S1N * 4 + 15) & ~15)
#define PSEMS_BYTES ((size_t)TP_TOTAL * NCH_PAD * 4)

// ---------------------------------------------------------------------------
// K1: fused  [peaks15 tiles | sems transpose]  (independent work, one launch)
// NOTE: do NOT fuse this into the paint kernel — the 20KB LDS branch caps the
// whole kernel's VGPR budget at 64 and serializes paint's gathers (R11: 196µs).
// ---------------------------------------------------------------------------
__global__ __launch_bounds__(256) void prep_kernel(
    const float* __restrict__ sems,
    const float* __restrict__ hm,
    float* __restrict__ ps,
    float* __restrict__ s1score,
    int* __restrict__ s1idx,
    int use_ps)
{
    const int bid = blockIdx.x;
    const int tid = threadIdx.x;

    __shared__ float sA[SH * SP];
    __shared__ float hx[SH * TW];
    __shared__ float lsc[TW * TH];
    __shared__ int   lix[TW * TH];
    __shared__ int   lcnt;

    if (bid >= PEAK_BLOCKS) {
        // ---- transpose part: sems [cam][c][v][u] -> ps [cam][v][u][c pad12]
        const int t = (bid - PEAK_BLOCKS) * 256 + tid;
        if (t >= TP_TOTAL) return;
        const int u = t & (RGB_W - 1);
        const int v = (t >> 8) % RGB_H;
        const int cam = t / (RGB_H * RGB_W);
        float vals[NCH_PAD];
#pragma unroll
        for (int c = 0; c < NCH; ++c)
            vals[c] = sems[(((long long)cam * NCH + c) * RGB_H + v) * RGB_W + u];
        vals[10] = 0.0f; vals[11] = 0.0f;
        f4* dst = (f4*)(ps + (size_t)t * NCH_PAD);
        dst[0] = (f4){vals[0], vals[1], vals[2],  vals[3]};
        dst[1] = (f4){vals[4], vals[5], vals[6],  vals[7]};
        dst[2] = (f4){vals[8], vals[9], vals[10], vals[11]};
        return;
    }

    // ---- peaks part: separable 7x7 SAME max-pool peak detect + tile top-15
    const int m  = bid / TILES_PER_MAP;
    const int tt = bid % TILES_PER_MAP;
    const int gx0 = (tt % NTILE_X) * TW;
    const int gy0 = (tt / NTILE_X) * TH;
    const int tx = tid & 63;
    const int ty = tid >> 6;     // 0..3
    const float* h = hm + (long long)m * HM_S * HM_S;

    if (tid == 0) lcnt = 0;
    __syncthreads();

    for (int yy = ty; yy < SH; yy += 4) {
        const int gv = gy0 + yy - 3;
        const bool vok = (gv >= 0) & (gv < HM_S);
        for (int xx = tx; xx < SW; xx += 64) {
            const int gu = gx0 + xx - 3;
            float val = -INFINITY;
            if (vok & (gu >= 0) & (gu < HM_S)) val = h[gv * HM_S + gu];
            sA[yy * SP + xx] = val;
        }
    }
    __syncthreads();

    for (int yy = ty; yy < SH; yy += 4) {
        const float* r = sA + yy * SP + tx;
        float mx = r[0];
#pragma unroll
        for (int k = 1; k < 7; ++k) mx = fmaxf(mx, r[k]);
        hx[yy * TW + tx] = mx;
    }
    __syncthreads();

    for (int ry = ty; ry < TH; ry += 4) {
        const float val = sA[(ry + 3) * SP + tx + 3];
        float mx = hx[ry * TW + tx];
#pragma unroll
        for (int k = 1; k < 7; ++k) mx = fmaxf(mx, hx[(ry + k) * TW + tx]);
        if (!(mx > val)) {
            int pos = atomicAdd(&lcnt, 1);   // LDS atomic
            lsc[pos] = val;
            lix[pos] = (gy0 + ry) * HM_S + (gx0 + tx);
        }
    }
    __syncthreads();

    // wave 0: 15 x argmax over the (avg ~20) local candidates
    if (tid < 64) {
        const int n = lcnt;
        const int slot0 = (m * TILES_PER_MAP + tt) * MAX_DET_K;
        for (int t = 0; t < MAX_DET_K; ++t) {
            float bs = -INFINITY; int bi = 0x7fffffff; int bp = -1;
            for (int j = tid; j < n; j += 64) {
                const float s = lsc[j]; const int id = lix[j];
                if (s > bs || (s == bs && id < bi)) { bs = s; bi = id; bp = j; }
            }
#pragma unroll
            for (int off = 32; off > 0; off >>= 1) {
                const float os = __shfl_down(bs, off);
                const int   oi = __shfl_down(bi, off);
                const int   op = __shfl_down(bp, off);
                if (os > bs || (os == bs && oi < bi)) { bs = os; bi = oi; bp = op; }
            }
            bs = __shfl(bs, 0); bi = __shfl(bi, 0); bp = __shfl(bp, 0);
            if (tid == 0) {
                s1score[slot0 + t] = bs;
                s1idx[slot0 + t]   = bi;
                if (bp >= 0) lsc[bp] = -INFINITY;
            }
        }
    }
}

// ---------------------------------------------------------------------------
// K2: fused  [merge (blocks 0..1) | paint (blocks 2..)]
// Paint: projection arithmetic identical to R1 — do not touch rounding.
// Output stores are TEMPORAL (plain) — fully-overwritten lines combine in L2
// and evict once; nt 8B stores caused HBM write amplification at low occ (R9).
// ---------------------------------------------------------------------------
__global__ __launch_bounds__(256) void main_kernel(
    const float* __restrict__ lidar,
    const float* __restrict__ sems,
    const float* __restrict__ psems,
    int use_ps,
    const float* __restrict__ Km,
    const float* __restrict__ L2W,
    const float* __restrict__ W2C,
    float* __restrict__ out,
    int N,
    const float* __restrict__ s1score,
    const int* __restrict__ s1idx,
    float* __restrict__ out_scores,
    float* __restrict__ out_locs)
{
    const int tid = threadIdx.x;

    if (blockIdx.x < HM_N) {
        // ---- merge part: top-15 of 6000 entries, 24 register entries/thread
        const int m = blockIdx.x;
        const int lane = tid & 63;
        const int wv = tid >> 6;   // 0..3

        float es[RPT]; int ei[RPT];
#pragma unroll
        for (int e = 0; e < RPT; ++e) {
            const int j = e * 256 + tid;
            if (j < S1N) { es[e] = s1score[m * S1N + j]; ei[e] = s1idx[m * S1N + j]; }
            else         { es[e] = -INFINITY;            ei[e] = 0x7fffffff; }
        }

        __shared__ float bss[4];
        __shared__ int   bis[4];
        __shared__ int   bps[4];
        __shared__ int   fbp;

        for (int t = 0; t < MAX_DET_K; ++t) {
            float bs = -INFINITY; int bi = 0x7fffffff; int bp = -1;
#pragma unroll
            for (int e = 0; e < RPT; ++e) {
                if (es[e] > bs || (es[e] == bs && ei[e] < bi)) {
                    bs = es[e]; bi = ei[e]; bp = e * 256 + tid;
                }
            }
#pragma unroll
            for (int off = 32; off > 0; off >>= 1) {
                const float os = __shfl_down(bs, off);
                const int   oi = __shfl_down(bi, off);
                const int   op = __shfl_down(bp, off);
                if (os > bs || (os == bs && oi < bi)) { bs = os; bi = oi; bp = op; }
            }
            if (lane == 0) { bss[wv] = bs; bis[wv] = bi; bps[wv] = bp; }
            __syncthreads();
            if (tid == 0) {
                float s = bss[0]; int i0 = bis[0]; int p = bps[0];
#pragma unroll
                for (int w = 1; w < 4; ++w) {
                    if (bss[w] > s || (bss[w] == s && bis[w] < i0)) {
                        s = bss[w]; i0 = bis[w]; p = bps[w];
                    }
                }
                out_scores[m * MAX_DET_K + t] = s;
                out_locs[m * MAX_DET_K + t]   = (float)i0;
                fbp = p;
            }
            __syncthreads();
            const int wbp = fbp;
            if (wbp >= 0 && (wbp & 255) == tid) es[wbp >> 8] = -INFINITY;
            __syncthreads();
        }
        return;
    }

    // ---- paint part: 4 points/thread, no LDS, 12 gathers in flight
    const long long base = (long long)(blockIdx.x - HM_N) * PBLK;

    long long gofs[IPT];   // psems pixel offset, -1 invalid, -2 out of range
#pragma unroll
    for (int k = 0; k < IPT; ++k) {
        const long long p = base + k * 256 + tid;
        f4 pt = (f4){0.f, 0.f, 0.f, 0.f};
        if (p < N) pt = __builtin_nontemporal_load(((const f4*)lidar) + p);
        const float x = pt.x, y = pt.y, z = pt.z;

        float w[3];
#pragma unroll
        for (int i = 0; i < 3; ++i) {
            float acc = L2W[4*i+0] * x;
            acc = fmaf(L2W[4*i+1], y, acc);
            acc = fmaf(L2W[4*i+2], z, acc);
            acc = fmaf(L2W[4*i+3], 1.0f, acc);
            w[i] = acc;
        }

        int sel = -1, su = 0, sv = 0;
#pragma unroll
        for (int i = 0; i < 3; ++i) {
            const float* W = W2C + 16 * i;
            float cam[3];
#pragma unroll
            for (int r = 0; r < 3; ++r) {
                float acc = W[4*r+0] * w[0];
                acc = fmaf(W[4*r+1], w[1], acc);
                acc = fmaf(W[4*r+2], w[2], acc);
                acc = fmaf(W[4*r+3], 1.0f, acc);
                cam[r] = acc;
            }
            const float c30 = cam[1], c31 = -cam[2], c32 = cam[0];
            float pr[3];
#pragma unroll
            for (int r = 0; r < 3; ++r) {
                float acc = Km[3*r+0] * c30;
                acc = fmaf(Km[3*r+1], c31, acc);
                acc = fmaf(Km[3*r+2], c32, acc);
                pr[r] = acc;
            }
            const float zz = 1e-5f + pr[2];
            const int u  = __float2int_rz(pr[0] / zz);
            const int v  = __float2int_rz(pr[1] / zz);
            const int zi = __float2int_rz(pr[2]);
            const bool valid = (zi >= 0) & (u >= 0) & (u < RGB_W)
                             & (v >= 0) & (v < RGB_H);
            if (valid) { sel = i; su = u; sv = v; }
        }
        gofs[k] = (sel >= 0)
                ? ((long long)sel * RGB_H + sv) * RGB_W + su
                : -1;
        if (p >= N) gofs[k] = -2;  // fully skip
    }

    f4 ga[IPT], gb[IPT]; f2 gc[IPT];
    if (use_ps) {
#pragma unroll
        for (int k = 0; k < IPT; ++k) {
            ga[k] = (f4){0,0,0,0}; gb[k] = (f4){0,0,0,0}; gc[k] = (f2){0,0};
            if (gofs[k] >= 0) {
                const f4* g = (const f4*)(psems + gofs[k] * NCH_PAD);
                ga[k] = g[0]; gb[k] = g[1];
                const f2* g2 = (const f2*)(g + 2);
                gc[k] = g2[0];
            }
        }
    } else {
#pragma unroll
        for (int k = 0; k < IPT; ++k) {
            ga[k] = (f4){0,0,0,0}; gb[k] = (f4){0,0,0,0}; gc[k] = (f2){0,0};
            if (gofs[k] >= 0) {
                const int sel = (int)(gofs[k] / (RGB_H * RGB_W));
                const int pix = (int)(gofs[k] % (RGB_H * RGB_W));
                const float* s = sems + ((long long)sel * NCH) * RGB_H * RGB_W + pix;
                const long long pl = (long long)RGB_H * RGB_W;
                ga[k] = (f4){s[0], s[pl], s[2*pl], s[3*pl]};
                gb[k] = (f4){s[4*pl], s[5*pl], s[6*pl], s[7*pl]};
                gc[k] = (f2){s[8*pl], s[9*pl]};
            }
        }
    }

#pragma unroll
    for (int k = 0; k < IPT; ++k) {
        const long long p = base + k * 256 + tid;
        if (gofs[k] == -2) continue;
        f2* o = (f2*)(out + p * NCH);   // p*40 bytes — always 8-aligned
        o[0] = (f2){ga[k].x, ga[k].y};
        o[1] = (f2){ga[k].z, ga[k].w};
        o[2] = (f2){gb[k].x, gb[k].y};
        o[3] = (f2){gb[k].z, gb[k].w};
        o[4] = gc[k];
    }
}

extern "C" void kernel_launch(void* const* d_in, const int* in_sizes, int n_in,
                              void* d_out, int out_size, void* d_ws, size_t ws_size,
                              hipStream_t stream)
{
    const float* lidar = (const float*)d_in[0];
    const float* sems  = (const float*)d_in[1];
    const float* hm    = (const float*)d_in[2];
    const float* Km    = (const float*)d_in[3];
    const float* L2W   = (const float*)d_in[4];
    const float* W2C   = (const float*)d_in[5];
    float* out = (float*)d_out;
    const int N = in_sizes[0] / 4;

    char* ws = (char*)d_ws;
    float* s1score = (float*)(ws + WS_S1SCORE);
    int*   s1idx   = (int*)(ws + WS_S1IDX);
    float* psems   = (float*)(ws + WS_PSEMS);
    const int use_ps = (ws_size >= (size_t)WS_PSEMS + PSEMS_BYTES) ? 1 : 0;

    // K1: peaks tiles + sems transpose (independent)
    const int k1_blocks = PEAK_BLOCKS + (use_ps ? TP_BLOCKS : 0);
    prep_kernel<<<k1_blocks, 256, 0, stream>>>(sems, hm, psems, s1score, s1idx, use_ps);

    // K2: merge (blocks 0..1) + paint (rest)
    float* out_scores = out + (long long)N * NCH;
    float* out_locs   = out_scores + HM_N * MAX_DET_K;
    const int paint_blocks = (int)((N + PBLK - 1) / PBLK);
    main_kernel<<<HM_N + paint_blocks, 256, 0, stream>>>(
        lidar, sems, psems, use_ps, Km, L2W, W2C, out, N,
        s1score, s1idx, out_scores, out_locs);
}